// Round 6
// baseline (536.908 us; speedup 1.0000x reference)
//
#include <hip/hip_runtime.h>
#include <hip/hip_fp16.h>
#include <math.h>

#define HID 64
#define IN_DIM 128
#define POS_DIM 64
#define FT_IN 192
#define BN_EPS 1e-5f
#define PAD 68   // LDS row stride (floats): 272B, 16B-aligned, conflict-light

static inline size_t align256(size_t x){ return (x + 255) & ~(size_t)255; }

// ---------------- CSR build ----------------

__global__ void k_init(float* deg, int* cnt, float* statsAll, int n){
  int i = blockIdx.x*blockDim.x + threadIdx.x;
  if (i < n){ deg[i] = 0.f; cnt[i] = 0; }
  if (i < 512) statsAll[i] = 0.f;
}

__global__ void k_degcnt(const int* __restrict__ col, const float* __restrict__ ew,
                         float* deg, int* cnt, int E){
  int e = blockIdx.x*blockDim.x + threadIdx.x;
  if (e < E){
    int c = col[e];
    atomicAdd(&deg[c], ew[e]);
    atomicAdd(&cnt[c], 1);
  }
}

__global__ void k_scanA(const int* __restrict__ cnt, int* ptr, int* bsum, int n){
  __shared__ int buf[256];
  int i = blockIdx.x*256 + threadIdx.x;
  int v = (i < n) ? cnt[i] : 0;
  buf[threadIdx.x] = v;
  __syncthreads();
  for (int off = 1; off < 256; off <<= 1){
    int t = (threadIdx.x >= off) ? buf[threadIdx.x - off] : 0;
    __syncthreads();
    buf[threadIdx.x] += t;
    __syncthreads();
  }
  if (i < n) ptr[i] = buf[threadIdx.x] - v;
  if (threadIdx.x == 255) bsum[blockIdx.x] = buf[255];
}

__global__ void k_scanB(int* bsum, int* ptr, int nblk, int n){
  __shared__ int buf[256];
  int v = (threadIdx.x < nblk) ? bsum[threadIdx.x] : 0;
  buf[threadIdx.x] = v;
  __syncthreads();
  for (int off = 1; off < 256; off <<= 1){
    int t = (threadIdx.x >= off) ? buf[threadIdx.x - off] : 0;
    __syncthreads();
    buf[threadIdx.x] += t;
    __syncthreads();
  }
  if (threadIdx.x < nblk) bsum[threadIdx.x] = buf[threadIdx.x] - v;
  if (threadIdx.x == 255) ptr[n] = buf[255];
}

// fused: finalize scan + dinv = rsqrt(deg+1)
__global__ void k_scanC(int* ptr, const int* __restrict__ bsum, int* fill,
                        const float* __restrict__ deg, float* dinv, int n){
  int i = blockIdx.x*blockDim.x + threadIdx.x;
  if (i < n){
    int p = ptr[i] + bsum[i >> 8];
    ptr[i] = p;
    fill[i] = p;
    dinv[i] = rsqrtf(deg[i] + 1.0f);
  }
}

// edges[p] = {src, bits(norm)} interleaved for one-load edge metadata
__global__ void k_fill(const int* __restrict__ row, const int* __restrict__ col,
                       const float* __restrict__ ew, const float* __restrict__ dinv,
                       int* fill, int2* edges, int E){
  int e = blockIdx.x*blockDim.x + threadIdx.x;
  if (e < E){
    int c = col[e], r = row[e];
    int p = atomicAdd(&fill[c], 1);
    float nrm = dinv[r]*ew[e]*dinv[c];
    edges[p] = make_int2(r, __float_as_int(nrm));
  }
}

// ---------------- register-tiled GEMM building block ----------------

#define MICRO_FMA(a, b, acc)                                   \
  acc[0].x = fmaf(a.x, b.x, acc[0].x);                         \
  acc[0].y = fmaf(a.x, b.y, acc[0].y);                         \
  acc[0].z = fmaf(a.x, b.z, acc[0].z);                         \
  acc[0].w = fmaf(a.x, b.w, acc[0].w);                         \
  acc[1].x = fmaf(a.y, b.x, acc[1].x);                         \
  acc[1].y = fmaf(a.y, b.y, acc[1].y);                         \
  acc[1].z = fmaf(a.y, b.z, acc[1].z);                         \
  acc[1].w = fmaf(a.y, b.w, acc[1].w);                         \
  acc[2].x = fmaf(a.z, b.x, acc[2].x);                         \
  acc[2].y = fmaf(a.z, b.y, acc[2].y);                         \
  acc[2].z = fmaf(a.z, b.z, acc[2].z);                         \
  acc[2].w = fmaf(a.z, b.w, acc[2].w);                         \
  acc[3].x = fmaf(a.w, b.x, acc[3].x);                         \
  acc[3].y = fmaf(a.w, b.y, acc[3].y);                         \
  acc[3].z = fmaf(a.w, b.z, acc[3].z);                         \
  acc[3].w = fmaf(a.w, b.w, acc[3].w);

// h0 = concat(x, pe) @ ftW ; bias skipped (cancels in BN); fused BN stats.
__global__ __launch_bounds__(256) void k_h0(
    const float* __restrict__ x, const int* __restrict__ positions,
    const float* __restrict__ ftW, float* __restrict__ h0, float* stats, int N)
{
  __shared__ __align__(16) float Xs[32*PAD];   // transposed [k][node]
  __shared__ __align__(16) float Wc[32*64];    // [k][col]
  __shared__ float redS[16*64];
  __shared__ float redQ[16*64];
  int tx = threadIdx.x;
  int n0 = blockIdx.x * 64;
  int c4 = (tx & 15) * 4;
  int r4 = (tx >> 4) * 4;
  float4 acc[4];
  acc[0] = acc[1] = acc[2] = acc[3] = make_float4(0.f,0.f,0.f,0.f);

  for (int kc = 0; kc < 6; ++kc){
    #pragma unroll
    for (int i = 0; i < 8; ++i)
      Wc[tx + i*256] = ftW[kc*2048 + tx + i*256];
    if (kc < 4){
      #pragma unroll
      for (int i = 0; i < 2; ++i){
        int s = tx + i*256;
        int row = s >> 3, kk = (s & 7) * 4;
        float4 v = make_float4(0.f,0.f,0.f,0.f);
        int n = n0 + row;
        if (n < N) v = *(const float4*)&x[(size_t)n*IN_DIM + kc*32 + kk];
        Xs[(kk+0)*PAD + row] = v.x;
        Xs[(kk+1)*PAD + row] = v.y;
        Xs[(kk+2)*PAD + row] = v.z;
        Xs[(kk+3)*PAD + row] = v.w;
      }
    } else {
      #pragma unroll
      for (int i = 0; i < 4; ++i){
        int s = tx + i*256;
        int m = s & 63, jj = s >> 6;
        int j = (kc-4)*16 + jj;
        int n = n0 + m;
        float sv = 0.f, cv = 0.f;
        if (n < N){
          float ang = (float)positions[n] * expf((float)(2*j) * -0.14391157f);
          sv = sinf(ang); cv = cosf(ang);
        }
        Xs[(2*jj+0)*PAD + m] = sv;
        Xs[(2*jj+1)*PAD + m] = cv;
      }
    }
    __syncthreads();
    #pragma unroll 8
    for (int k = 0; k < 32; ++k){
      float4 a = *(const float4*)(Xs + k*PAD + r4);
      float4 b = *(const float4*)(Wc + k*64 + c4);
      MICRO_FMA(a, b, acc);
    }
    __syncthreads();
  }

  float cs[4] = {0,0,0,0}, cq[4] = {0,0,0,0};
  #pragma unroll
  for (int i = 0; i < 4; ++i){
    int n = n0 + r4 + i;
    if (n < N) *(float4*)&h0[(size_t)n*HID + c4] = acc[i];
    float4 v = (n < N) ? acc[i] : make_float4(0,0,0,0);
    cs[0] += v.x; cs[1] += v.y; cs[2] += v.z; cs[3] += v.w;
    cq[0] += v.x*v.x; cq[1] += v.y*v.y; cq[2] += v.z*v.z; cq[3] += v.w*v.w;
  }
  int g = tx >> 4;
  #pragma unroll
  for (int j = 0; j < 4; ++j){
    redS[g*64 + c4 + j] = cs[j];
    redQ[g*64 + c4 + j] = cq[j];
  }
  __syncthreads();
  if (tx < 64){
    float s = 0.f, q = 0.f;
    #pragma unroll
    for (int gg = 0; gg < 16; ++gg){ s += redS[gg*64 + tx]; q += redQ[gg*64 + tx]; }
    atomicAdd(&stats[tx], s);
    atomicAdd(&stats[64+tx], q);
  }
}

// fused: coef from stats (inline BN finalize); h_new = relu(aggb*scale+shift)
// (+ hbuf if residual); hbuf = h_new; hw = h_new @ W (fp16, split feature halves)
__global__ __launch_bounds__(256) void k_layer(
    const float* __restrict__ aggb, const float* __restrict__ stats,
    const float* __restrict__ gamma, const float* __restrict__ beta, float invN,
    float* __restrict__ hbuf, const float* __restrict__ W,
    __half* __restrict__ hwhA, __half* __restrict__ hwhB, int N, int residual)
{
  __shared__ __align__(16) float Ws[64*64];
  __shared__ __align__(16) float Hs[64*PAD];
  __shared__ float coefS[128];
  int tx = threadIdx.x;
  int n0 = blockIdx.x * 64;
  if (tx < 64){
    float s = stats[tx], s2 = stats[64+tx];
    float mean = s * invN;
    float var = s2 * invN - mean*mean;
    float scale = rsqrtf(var + BN_EPS) * gamma[tx];
    coefS[tx] = scale;
    coefS[64+tx] = beta[tx] - mean*scale;
  }
  #pragma unroll
  for (int i = 0; i < 16; ++i) Ws[tx + i*256] = W[tx + i*256];
  __syncthreads();
  #pragma unroll
  for (int i = 0; i < 4; ++i){
    int s = tx + i*256;
    int row = s >> 4, cc = (s & 15) * 4;
    int n = n0 + row;
    float4 r = make_float4(0.f,0.f,0.f,0.f);
    if (n < N){
      float4 v = *(const float4*)&aggb[(size_t)n*HID + cc];
      r.x = fmaxf(fmaf(v.x, coefS[cc+0], coefS[64+cc+0]), 0.f);
      r.y = fmaxf(fmaf(v.y, coefS[cc+1], coefS[64+cc+1]), 0.f);
      r.z = fmaxf(fmaf(v.z, coefS[cc+2], coefS[64+cc+2]), 0.f);
      r.w = fmaxf(fmaf(v.w, coefS[cc+3], coefS[64+cc+3]), 0.f);
      if (residual){
        float4 o = *(const float4*)&hbuf[(size_t)n*HID + cc];
        r.x += o.x; r.y += o.y; r.z += o.z; r.w += o.w;
      }
      *(float4*)&hbuf[(size_t)n*HID + cc] = r;
    }
    Hs[(cc+0)*PAD + row] = r.x;
    Hs[(cc+1)*PAD + row] = r.y;
    Hs[(cc+2)*PAD + row] = r.z;
    Hs[(cc+3)*PAD + row] = r.w;
  }
  __syncthreads();
  int c4 = (tx & 15) * 4;
  int r4 = (tx >> 4) * 4;
  float4 acc[4];
  acc[0] = acc[1] = acc[2] = acc[3] = make_float4(0.f,0.f,0.f,0.f);
  #pragma unroll 8
  for (int k = 0; k < 64; ++k){
    float4 a = *(const float4*)(Hs + k*PAD + r4);
    float4 b = *(const float4*)(Ws + k*64 + c4);
    MICRO_FMA(a, b, acc);
  }
  #pragma unroll
  for (int i = 0; i < 4; ++i){
    int n = n0 + r4 + i;
    if (n < N){
      __half2 h01 = __floats2half2_rn(acc[i].x, acc[i].y);
      __half2 h23 = __floats2half2_rn(acc[i].z, acc[i].w);
      __half* dst = (c4 < 32) ? (hwhA + (size_t)n*32 + c4)
                              : (hwhB + (size_t)n*32 + (c4 - 32));
      *(__half2*)&dst[0] = h01;
      *(__half2*)&dst[2] = h23;
    }
  }
}

// agg[n][halfOff+f] = dinv[n]^2*hw[n][f] + sum_e norm[e]*hw[src[e]][f]
// over a 32-feature half whose buffer (3.2MB) is per-XCD L2-resident.
// lane = feature pair (half2), 16 lanes/edge -> 4 edges per gather instr,
// 4 independent chains (16 edges in flight); zero-padded metadata, no tails.
__global__ __launch_bounds__(256) void k_agg(
    const __half* __restrict__ hwhHalf, const int* __restrict__ ptr,
    const int2* __restrict__ edges, const float* __restrict__ dinv,
    float* __restrict__ agg, float* stats, int N, int halfOff)
{
  __shared__ float redS[4*32];
  __shared__ float redQ[4*32];
  int tx = threadIdx.x;
  int lane = tx & 63, w = tx >> 6;
  int sub = lane >> 4;       // edge slot 0..3 within a gather instruction
  int f2 = lane & 15;        // feature pair index: features 2f2, 2f2+1
  float2 csum = make_float2(0.f,0.f), csq = make_float2(0.f,0.f);
  int n0 = blockIdx.x*16 + w*4;
  for (int it = 0; it < 4; ++it){
    int n = n0 + it;
    if (n >= N) break;                    // wave-uniform
    float2 a0 = make_float2(0.f,0.f), a1 = a0, a2 = a0, a3 = a0;
    {
      float di = dinv[n];
      float2 f = __half22float2(*(const __half2*)&hwhHalf[(size_t)n*32 + 2*f2]);
      if (sub == 0){ float d2 = di*di; a0.x = d2*f.x; a0.y = d2*f.y; }
    }
    int e0 = ptr[n], e1 = ptr[n+1];
    for (int eb = e0; eb < e1; eb += 64){
      int m = e1 - eb; if (m > 64) m = 64;
      int2 md = (lane < m) ? edges[eb + lane] : make_int2(0,0);
      for (int j = 0; j < m; j += 16){
        int   s0 = __shfl(md.x, j + sub,      64);
        float w0 = __int_as_float(__shfl(md.y, j + sub,      64));
        int   s1 = __shfl(md.x, j + 4 + sub,  64);
        float w1 = __int_as_float(__shfl(md.y, j + 4 + sub,  64));
        int   s2 = __shfl(md.x, j + 8 + sub,  64);
        float w2 = __int_as_float(__shfl(md.y, j + 8 + sub,  64));
        int   s3 = __shfl(md.x, j + 12 + sub, 64);
        float w3 = __int_as_float(__shfl(md.y, j + 12 + sub, 64));
        float2 g0 = __half22float2(*(const __half2*)&hwhHalf[(size_t)s0*32 + 2*f2]);
        float2 g1 = __half22float2(*(const __half2*)&hwhHalf[(size_t)s1*32 + 2*f2]);
        float2 g2 = __half22float2(*(const __half2*)&hwhHalf[(size_t)s2*32 + 2*f2]);
        float2 g3 = __half22float2(*(const __half2*)&hwhHalf[(size_t)s3*32 + 2*f2]);
        a0.x = fmaf(w0, g0.x, a0.x); a0.y = fmaf(w0, g0.y, a0.y);
        a1.x = fmaf(w1, g1.x, a1.x); a1.y = fmaf(w1, g1.y, a1.y);
        a2.x = fmaf(w2, g2.x, a2.x); a2.y = fmaf(w2, g2.y, a2.y);
        a3.x = fmaf(w3, g3.x, a3.x); a3.y = fmaf(w3, g3.y, a3.y);
      }
    }
    a0.x = (a0.x + a1.x) + (a2.x + a3.x);
    a0.y = (a0.y + a1.y) + (a2.y + a3.y);
    a0.x += __shfl_xor(a0.x, 16, 64);
    a0.y += __shfl_xor(a0.y, 16, 64);
    a0.x += __shfl_xor(a0.x, 32, 64);
    a0.y += __shfl_xor(a0.y, 32, 64);
    if (lane < 16){
      *(float2*)&agg[(size_t)n*HID + halfOff + 2*f2] = a0;
      csum.x += a0.x; csum.y += a0.y;
      csq.x += a0.x*a0.x; csq.y += a0.y*a0.y;
    }
  }
  if (lane < 16){
    *(float2*)&redS[w*32 + 2*f2] = csum;
    *(float2*)&redQ[w*32 + 2*f2] = csq;
  }
  __syncthreads();
  if (tx < 32){
    float s = redS[tx] + redS[32+tx] + redS[64+tx] + redS[96+tx];
    float q = redQ[tx] + redQ[32+tx] + redQ[64+tx] + redQ[96+tx];
    atomicAdd(&stats[halfOff + tx], s);
    atomicAdd(&stats[64 + halfOff + tx], q);
  }
}

// fused final: coef inline; h3 = relu(aggb*scale+shift)+hbuf ;
// out = relu(h3@W1+b1)@W2+b2
__global__ __launch_bounds__(256) void k_out(
    const float* __restrict__ aggb, const float* __restrict__ stats,
    const float* __restrict__ gamma, const float* __restrict__ beta, float invN,
    const float* __restrict__ hbuf,
    const float* __restrict__ W1, const float* __restrict__ b1,
    const float* __restrict__ W2, const float* __restrict__ b2,
    float* __restrict__ out, int N)
{
  __shared__ __align__(16) float Hs[64*PAD];
  __shared__ float red[256];
  __shared__ float coefS[128];
  int tx = threadIdx.x;
  int n0 = blockIdx.x * 64;
  if (tx < 64){
    float s = stats[tx], s2 = stats[64+tx];
    float mean = s * invN;
    float var = s2 * invN - mean*mean;
    float scale = rsqrtf(var + BN_EPS) * gamma[tx];
    coefS[tx] = scale;
    coefS[64+tx] = beta[tx] - mean*scale;
  }
  __syncthreads();
  #pragma unroll
  for (int i = 0; i < 4; ++i){
    int s = tx + i*256;
    int row = s >> 4, cc = (s & 15) * 4;
    int n = n0 + row;
    float4 r = make_float4(0.f,0.f,0.f,0.f);
    if (n < N){
      float4 v = *(const float4*)&aggb[(size_t)n*HID + cc];
      r.x = fmaxf(fmaf(v.x, coefS[cc+0], coefS[64+cc+0]), 0.f);
      r.y = fmaxf(fmaf(v.y, coefS[cc+1], coefS[64+cc+1]), 0.f);
      r.z = fmaxf(fmaf(v.z, coefS[cc+2], coefS[64+cc+2]), 0.f);
      r.w = fmaxf(fmaf(v.w, coefS[cc+3], coefS[64+cc+3]), 0.f);
      float4 o = *(const float4*)&hbuf[(size_t)n*HID + cc];
      r.x += o.x; r.y += o.y; r.z += o.z; r.w += o.w;
    }
    Hs[(cc+0)*PAD + row] = r.x;
    Hs[(cc+1)*PAD + row] = r.y;
    Hs[(cc+2)*PAD + row] = r.z;
    Hs[(cc+3)*PAD + row] = r.w;
  }
  __syncthreads();
  int m = tx & 63, w = tx >> 6, j0 = w*8;
  float acc[8] = {0,0,0,0,0,0,0,0};
  #pragma unroll 8
  for (int k = 0; k < 64; ++k){
    float hv = Hs[k*PAD + m];
    #pragma unroll
    for (int j = 0; j < 8; ++j)
      acc[j] = fmaf(hv, W1[k*32 + j0 + j], acc[j]);
  }
  float part = 0.f;
  #pragma unroll
  for (int j = 0; j < 8; ++j)
    part += fmaxf(acc[j] + b1[j0+j], 0.f) * W2[j0+j];
  red[w*64 + m] = part;
  __syncthreads();
  if (tx < 64){
    int n = n0 + tx;
    if (n < N) out[n] = red[tx] + red[64+tx] + red[128+tx] + red[192+tx] + b2[0];
  }
}

extern "C" void kernel_launch(void* const* d_in, const int* in_sizes, int n_in,
                              void* d_out, int out_size, void* d_ws, size_t ws_size,
                              hipStream_t stream)
{
  const float* x         = (const float*)d_in[0];
  const int*   ei        = (const int*)d_in[1];
  const float* ew        = (const float*)d_in[2];
  const int*   positions = (const int*)d_in[3];
  const float* ftW       = (const float*)d_in[4];
  const float* ft_gamma  = (const float*)d_in[6];
  const float* ft_beta   = (const float*)d_in[7];
  const float* convW     = (const float*)d_in[8];
  const float* bn_gamma  = (const float*)d_in[10];
  const float* bn_beta   = (const float*)d_in[11];
  const float* outW1     = (const float*)d_in[12];
  const float* outb1     = (const float*)d_in[13];
  const float* outW2     = (const float*)d_in[14];
  const float* outb2     = (const float*)d_in[15];
  float* out = (float*)d_out;

  int N = in_sizes[0] / IN_DIM;
  int E = in_sizes[1] / 2;
  const int* row  = ei;
  const int* colv = ei + E;

  char* p = (char*)d_ws;
  auto alloc = [&](size_t bytes){ char* r = p; p += align256(bytes); return r; };
  float* deg      = (float*)alloc((size_t)N*4);
  float* dinv     = (float*)alloc((size_t)N*4);
  int*   cnt      = (int*)  alloc((size_t)N*4);
  int*   ptr      = (int*)  alloc((size_t)(N+1)*4);
  int*   fill     = (int*)  alloc((size_t)N*4);
  int*   bsum     = (int*)  alloc((size_t)((N+255)/256)*4);
  int2*  edges    = (int2*) alloc((size_t)E*8);
  __half* hwhA    = (__half*)alloc((size_t)N*32*2);
  __half* hwhB    = (__half*)alloc((size_t)N*32*2);
  float* aggb     = (float*)alloc((size_t)N*HID*4);
  float* hbuf     = (float*)alloc((size_t)N*HID*4);
  float* statsAll = (float*)alloc(512*4);   // 4 x 128 (ft, layer0..2)

  float* stats0 = statsAll;
  float* stats1 = statsAll + 128;
  float* stats2 = statsAll + 256;
  float* stats3 = statsAll + 384;

  int nb_n  = (N+255)/256;
  int nb_e  = (E+255)/256;
  int nblk  = (N+255)/256;
  int nb64  = (N+63)/64;
  int nb16  = (N+15)/16;
  float invN = 1.0f/(float)N;

  // CSR build (once; shared by all 3 layers)
  k_init  <<<nb_n,256,0,stream>>>(deg,cnt,statsAll,N);
  k_degcnt<<<nb_e,256,0,stream>>>(colv,ew,deg,cnt,E);
  k_scanA <<<nblk,256,0,stream>>>(cnt,ptr,bsum,N);
  k_scanB <<<1,256,0,stream>>>(bsum,ptr,nblk,N);
  k_scanC <<<nb_n,256,0,stream>>>(ptr,bsum,fill,deg,dinv,N);
  k_fill  <<<nb_e,256,0,stream>>>(row,colv,ew,dinv,fill,edges,E);

  // feature transform (pre-BN values -> aggb, stats fused)
  k_h0  <<<nb64,256,0,stream>>>(x,positions,ftW,aggb,stats0,N);

  // GCN layers (BN coef computed inline from stats of the previous stage)
  float* statsIn[4]  = {stats0, stats1, stats2, stats3};
  for (int i = 0; i < 3; ++i){
    const float* g = (i==0) ? ft_gamma : bn_gamma + (size_t)(i-1)*HID;
    const float* b = (i==0) ? ft_beta  : bn_beta  + (size_t)(i-1)*HID;
    k_layer<<<nb64,256,0,stream>>>(aggb,statsIn[i],g,b,invN,hbuf,
                                   convW + (size_t)i*HID*HID,hwhA,hwhB,N,(i>0)?1:0);
    k_agg  <<<nb16,256,0,stream>>>(hwhA,ptr,edges,dinv,aggb,statsIn[i+1],N,0);
    k_agg  <<<nb16,256,0,stream>>>(hwhB,ptr,edges,dinv,aggb,statsIn[i+1],N,32);
  }

  // final apply + output MLP
  k_out<<<nb64,256,0,stream>>>(aggb,stats3,bn_gamma+2*HID,bn_beta+2*HID,invN,
                               hbuf,outW1,outb1,outW2,outb2,out,N);
}